// Round 7
// baseline (17647.821 us; speedup 1.0000x reference)
//
#include <hip/hip_runtime.h>

// RNN: h_t = tanh(E[x_t] + h_{t-1} @ Whh + bh), T=1024, N=64, H=1024.
// y = softmax(z @ Wout + bout). Output: y (64*1024*256 f32) then h_last (64*1024 f32).
//
// Double-FP16 recurrence (hi + 2^-11*lo of h and Whh) -> fp32-equivalent
// per-step precision (R3/R5/R6: passed, absmax 9.8e-4).
// R7 changes (R6 was 12.25us/step: 1 wave/SIMD, A-loads ~2-3 deep at L2/L3
// latency fully exposed -> ~25k cy/step on the A stream; VGPR=132 proved the
// 128-VGPR prefetch plan never materialized):
//  - 1024-thread WGs: 16 waves = 4 waves/SIMD -> real TLP to hide A latency
//  - K=1024 split 4 ways across waves (wave(kq,nq): k in [kq*256,+256),
//    rows nq*16..+16); per-lane A-loads 64 -> 16; partials reduced via LDS
//  - LDS: e_s 16KB + Whh frags 64KB + reduce 16KB = 96KB

typedef _Float16 f16x8 __attribute__((ext_vector_type(8)));
typedef float    f32x4 __attribute__((ext_vector_type(4)));

#define NSEQ  64
#define TSEQ  1024
#define HDIM  1024
#define VOCABSZ 256
#define ODIM  256
#define NWG   64     // one WG per 16 columns of H
#define LOSCALE 2048.0f
#define LOINV  (1.0f/2048.0f)

// hbuf layout: [buf(2)][plane(2: hi,lo)][NSEQ][HDIM] fp16
#define HPLANE (NSEQ * HDIM)
#define HBUFSZ (2 * HPLANE)

// ---------------------------------------------------------------- init / prep
__global__ __launch_bounds__(256) void rnn_init(
    const float* __restrict__ Whh, const float* __restrict__ Wout,
    _Float16* __restrict__ whhT_hi, _Float16* __restrict__ whhT_lo,
    _Float16* __restrict__ woutT,
    _Float16* __restrict__ hbuf, unsigned* __restrict__ flags)
{
    int i = blockIdx.x * 256 + threadIdx.x;
    int stride = gridDim.x * 256;
    for (int idx = i; idx < HDIM * HDIM; idx += stride) {
        int j = idx >> 10, k = idx & 1023;
        float w = Whh[k * HDIM + j];
        _Float16 hi = (_Float16)w;
        whhT_hi[idx] = hi;
        whhT_lo[idx] = (_Float16)((w - (float)hi) * LOSCALE);
    }
    for (int idx = i; idx < ODIM * HDIM; idx += stride) {
        int o = idx >> 10, k = idx & 1023;
        woutT[idx] = (_Float16)Wout[k * ODIM + o];
    }
    for (int idx = i; idx < 2 * HBUFSZ; idx += stride) hbuf[idx] = (_Float16)0.f;
    for (int idx = i; idx < TSEQ * NWG; idx += stride) flags[idx] = 0u;
}

// ---------------------------------------------------------------- recurrence
__global__ __launch_bounds__(1024, 1) void rnn_steps(
    const int*   __restrict__ x,          // [NSEQ][TSEQ]
    const float* __restrict__ E,          // [VOCAB][HDIM]
    const float* __restrict__ bh,         // [HDIM]
    const _Float16* __restrict__ whhT_hi, // [HDIM][HDIM] j-major
    const _Float16* __restrict__ whhT_lo,
    _Float16* __restrict__ hbuf,
    unsigned* __restrict__ flags,         // [TSEQ][NWG]
    _Float16* __restrict__ z,             // chunk: [tc][NSEQ*HDIM]
    float* __restrict__ hlast_out,        // [NSEQ*HDIM]
    int t0, int t1)
{
    const int c   = blockIdx.x;        // column-group 0..63
    const int j0  = c * 16;
    const int tid = threadIdx.x;
    const int lane = tid & 63;
    const int wv   = tid >> 6;         // wave 0..15
    const int nq   = wv & 3;           // row quarter: rows nq*16..+16
    const int kq   = wv >> 2;          // k quarter:   k in [kq*256, +256)
    const int n0   = nq * 16;
    const int lr   = lane & 15;        // fragment row/col selector
    const int lq   = lane >> 4;        // k sub-chunk selector (0..3)

    __shared__ float    e_s[VOCABSZ][16];     // (E + bh) slice, 16 KB
    __shared__ _Float16 bls[2][32][64][8];    // Whh^T hi/lo fragments, 64 KB
    __shared__ f32x4    red[16][64];          // per-wave partial tiles, 16 KB

    if (tid < VOCABSZ) {   // stage E[:, j0:j0+16] + bh fold
        const float* src = E + (size_t)tid * HDIM + j0;
        #pragma unroll
        for (int jj = 0; jj < 16; ++jj) e_s[tid][jj] = src[jj] + bh[j0 + jj];
    }
    {   // stage B fragments: wave wv stages m = wv*2, wv*2+1
        const size_t boff = (size_t)(j0 + lr) * HDIM + lq * 8;
        #pragma unroll
        for (int mm = 0; mm < 2; ++mm) {
            const int m = wv * 2 + mm;
            *(f16x8*)&bls[0][m][lane][0] = *(const f16x8*)(whhT_hi + boff + m * 32);
            *(f16x8*)&bls[1][m][lane][0] = *(const f16x8*)(whhT_lo + boff + m * 32);
        }
    }
    __syncthreads();

    for (int t = t0; t < t1; ++t) {
        if (t > 0) {
            // wait for all 64 producers of h_t (step t-1): RELAXED polls
            unsigned* f = flags + (size_t)(t - 1) * NWG;
            while (!__all((int)(__hip_atomic_load(&f[lane], __ATOMIC_RELAXED,
                                                  __HIP_MEMORY_SCOPE_AGENT) != 0u)))
                __builtin_amdgcn_s_sleep(1);
            // one invalidate so cached h loads below can't hit stale L1/L2
            __builtin_amdgcn_fence(__ATOMIC_ACQUIRE, "agent");
        }
        const _Float16* hin_hi  = hbuf + (size_t)( t      & 1) * HBUFSZ;
        const _Float16* hin_lo  = hin_hi + HPLANE;
        _Float16*       hout_hi = hbuf + (size_t)((t + 1) & 1) * HBUFSZ;
        _Float16*       hout_lo = hout_hi + HPLANE;

        // A loads: this wave's 16 rows x its k-quarter; 8 hi + 8 lo vec loads,
        // all issued before the MFMA chain (64 VGPRs, compile-time indices).
        const _Float16* Ah = hin_hi + (size_t)(n0 + lr) * HDIM + kq * 256 + lq * 8;
        const _Float16* Al = hin_lo + (size_t)(n0 + lr) * HDIM + kq * 256 + lq * 8;
        f16x8 pah[8], pal[8];
        #pragma unroll
        for (int i = 0; i < 8; ++i) pah[i] = *(const f16x8*)(Ah + i * 32);
        #pragma unroll
        for (int i = 0; i < 8; ++i) pal[i] = *(const f16x8*)(Al + i * 32);

        f32x4 acc0 = {0.f, 0.f, 0.f, 0.f};
        f32x4 acc1 = {0.f, 0.f, 0.f, 0.f};
        #pragma unroll
        for (int i = 0; i < 8; ++i) {
            const int m = kq * 8 + i;
            f16x8 bhv = *(const f16x8*)&bls[0][m][lane][0];
            f16x8 blv = *(const f16x8*)&bls[1][m][lane][0];
            acc0 = __builtin_amdgcn_mfma_f32_16x16x32_f16(pah[i], bhv, acc0, 0, 0, 0);
            acc1 = __builtin_amdgcn_mfma_f32_16x16x32_f16(pal[i], bhv, acc1, 0, 0, 0);
            acc1 = __builtin_amdgcn_mfma_f32_16x16x32_f16(pah[i], blv, acc1, 0, 0, 0);
        }
        // partial for this k-quarter
        f32x4 part;
        #pragma unroll
        for (int r = 0; r < 4; ++r) part[r] = acc0[r] + acc1[r] * LOINV;
        red[wv][lane] = part;
        __syncthreads();

        // epilogue: kq==0 waves combine 4 partials and finish their 16 rows
        if (kq == 0) {
            f32x4 p1 = red[4 + nq][lane];
            f32x4 p2 = red[8 + nq][lane];
            f32x4 p3 = red[12 + nq][lane];
            int tok[4];
            #pragma unroll
            for (int r = 0; r < 4; ++r)
                tok[r] = x[(size_t)(n0 + lq * 4 + r) * TSEQ + t];

            _Float16* zrow = z + (size_t)(t - t0) * (NSEQ * HDIM);
            unsigned hb[4], lb[4];
            #pragma unroll
            for (int r = 0; r < 4; ++r) {
                int n = n0 + lq * 4 + r;
                int j = j0 + lr;
                float pre = part[r] + p1[r] + p2[r] + p3[r] + e_s[tok[r]][lr];
                float hv  = tanhf(pre);
                _Float16 h16 = (_Float16)hv;
                _Float16 l16 = (_Float16)((hv - (float)h16) * LOSCALE);
                union { _Float16 f; unsigned short u; } ch{h16}, cl{l16};
                hb[r] = ch.u; lb[r] = cl.u;
                zrow[(size_t)n * HDIM + j] = h16;                        // cached
                if (t == TSEQ - 1) hlast_out[(size_t)n * HDIM + j] = hv; // cached
            }
            // h exchange: bypass L1/L2 (sc0 sc1) -> at agent coherence point
            // once vmcnt(0) clears; no release fence needed.
            const _Float16* ah0 = hout_hi + (size_t)(n0 + lq * 4) * HDIM + j0 + lr;
            const _Float16* ah2 = ah0 + 2 * HDIM;
            const _Float16* al0 = hout_lo + (size_t)(n0 + lq * 4) * HDIM + j0 + lr;
            const _Float16* al2 = al0 + 2 * HDIM;
            asm volatile(
                "global_store_short %[ah0], %[h0], off sc0 sc1\n\t"
                "global_store_short %[ah0], %[h1], off offset:2048 sc0 sc1\n\t"
                "global_store_short %[ah2], %[h2], off sc0 sc1\n\t"
                "global_store_short %[ah2], %[h3], off offset:2048 sc0 sc1\n\t"
                "global_store_short %[al0], %[l0], off sc0 sc1\n\t"
                "global_store_short %[al0], %[l1], off offset:2048 sc0 sc1\n\t"
                "global_store_short %[al2], %[l2], off sc0 sc1\n\t"
                "global_store_short %[al2], %[l3], off offset:2048 sc0 sc1\n\t"
                "s_waitcnt vmcnt(0)"
                :
                : [ah0]"v"(ah0), [ah2]"v"(ah2), [al0]"v"(al0), [al2]"v"(al2),
                  [h0]"v"(hb[0]), [h1]"v"(hb[1]), [h2]"v"(hb[2]), [h3]"v"(hb[3]),
                  [l0]"v"(lb[0]), [l1]"v"(lb[1]), [l2]"v"(lb[2]), [l3]"v"(lb[3])
                : "memory");
        }
        __syncthreads();      // epilogue stores drained; red[] free for reuse
        if (tid == 0)
            __hip_atomic_store(&flags[(size_t)t * NWG + c], 1u,
                               __ATOMIC_RELAXED, __HIP_MEMORY_SCOPE_AGENT);
    }
}

// ---------------------------------------------------------------- output GEMM + softmax
__global__ __launch_bounds__(256, 1) void rnn_out(
    const _Float16* __restrict__ z,      // chunk: [tc][NSEQ*HDIM]
    const _Float16* __restrict__ woutT,  // [ODIM][HDIM]
    const float* __restrict__ bout,      // [ODIM]
    float* __restrict__ y,               // [NSEQ][TSEQ][ODIM]
    int t0, int tc)
{
    const int b = blockIdx.x;
    const int t_rel = b >> 2, ng = b & 3;
    const int t = t0 + t_rel;
    const int n0 = ng * 16;
    const int tid = threadIdx.x;
    const int lane = tid & 63, wv = tid >> 6;
    const int lr = lane & 15, lq = lane >> 4;

    __shared__ float lg[16][ODIM + 8];   // logits staging

    const _Float16* abase = z + (size_t)t_rel * (NSEQ * HDIM)
                              + (size_t)(n0 + lr) * HDIM + lq * 8;
    f16x8 af[32];
    #pragma unroll
    for (int m = 0; m < 32; ++m) af[m] = *(const f16x8*)(abase + m * 32);

    #pragma unroll
    for (int i = 0; i < 4; ++i) {
        int ot = (wv * 4 + i) * 16;
        const _Float16* bbase = woutT + (size_t)(ot + lr) * HDIM + lq * 8;
        f32x4 acc = {0.f, 0.f, 0.f, 0.f};
        #pragma unroll
        for (int m = 0; m < 32; ++m) {
            f16x8 bfr = *(const f16x8*)(bbase + m * 32);
            acc = __builtin_amdgcn_mfma_f32_16x16x32_f16(af[m], bfr, acc, 0, 0, 0);
        }
        #pragma unroll
        for (int r = 0; r < 4; ++r)
            lg[lq * 4 + r][ot + lr] = acc[r];
    }
    __syncthreads();

    for (int rr = 0; rr < 4; ++rr) {
        int row = wv * 4 + rr;
        int n = n0 + row;
        float v0 = lg[row][lane]       + bout[lane];
        float v1 = lg[row][64 + lane]  + bout[64 + lane];
        float v2 = lg[row][128 + lane] + bout[128 + lane];
        float v3 = lg[row][192 + lane] + bout[192 + lane];
        float mx = fmaxf(fmaxf(v0, v1), fmaxf(v2, v3));
        for (int s = 32; s > 0; s >>= 1) mx = fmaxf(mx, __shfl_xor(mx, s));
        float e0 = __expf(v0 - mx), e1 = __expf(v1 - mx);
        float e2 = __expf(v2 - mx), e3 = __expf(v3 - mx);
        float sm = e0 + e1 + e2 + e3;
        for (int s = 32; s > 0; s >>= 1) sm += __shfl_xor(sm, s);
        float inv = 1.f / sm;
        float* dst = y + ((size_t)n * TSEQ + t) * ODIM;
        dst[lane]       = e0 * inv;
        dst[64 + lane]  = e1 * inv;
        dst[128 + lane] = e2 * inv;
        dst[192 + lane] = e3 * inv;
    }
}

// ---------------------------------------------------------------- launch
extern "C" void kernel_launch(void* const* d_in, const int* in_sizes, int n_in,
                              void* d_out, int out_size, void* d_ws, size_t ws_size,
                              hipStream_t stream)
{
    const int*   x    = (const int*)  d_in[0];
    const float* E    = (const float*)d_in[1];
    const float* Whh  = (const float*)d_in[2];
    const float* bh   = (const float*)d_in[3];
    const float* Wout = (const float*)d_in[4];
    const float* bout = (const float*)d_in[5];

    float* y     = (float*)d_out;
    float* hlast = y + (size_t)NSEQ * TSEQ * ODIM;

    char* ws = (char*)d_ws;
    size_t off = 0;
    auto alloc = [&](size_t bytes) -> void* {
        void* p = ws + off;
        off = (off + bytes + 255) & ~(size_t)255;
        return p;
    };
    _Float16* whhT_hi = (_Float16*)alloc((size_t)HDIM * HDIM * 2);
    _Float16* whhT_lo = (_Float16*)alloc((size_t)HDIM * HDIM * 2);
    _Float16* woutT   = (_Float16*)alloc((size_t)ODIM * HDIM * 2);
    _Float16* hbuf    = (_Float16*)alloc((size_t)2 * HBUFSZ * 2);
    unsigned* flags   = (unsigned*)alloc((size_t)TSEQ * NWG * 4);
    _Float16* z       = (_Float16*)(ws + off);

    size_t zcap = (ws_size > off) ? (ws_size - off) : 0;
    int tc_max = (int)(zcap / ((size_t)NSEQ * HDIM * 2));
    if (tc_max > TSEQ) tc_max = TSEQ;
    if (tc_max < 1)    tc_max = 1;

    rnn_init<<<2048, 256, 0, stream>>>(Whh, Wout, whhT_hi, whhT_lo, woutT,
                                       hbuf, flags);

    for (int t0 = 0; t0 < TSEQ; t0 += tc_max) {
        int tc = TSEQ - t0 < tc_max ? TSEQ - t0 : tc_max;
        rnn_steps<<<NWG, 1024, 0, stream>>>(x, E, bh, whhT_hi, whhT_lo, hbuf,
                                            flags, z, hlast, t0, t0 + tc);
        rnn_out<<<tc * 4, 256, 0, stream>>>(z, woutT, bout, y, t0, tc);
    }
}

// Round 8
// 12065.195 us; speedup vs baseline: 1.4627x; 1.4627x over previous
//
#include <hip/hip_runtime.h>

// RNN: h_t = tanh(E[x_t] + h_{t-1} @ Whh + bh), T=1024, N=64, H=1024.
// y = softmax(z @ Wout + bout). Output: y (64*1024*256 f32) then h_last (64*1024 f32).
//
// Double-FP16 recurrence (hi + 2^-11*lo of h and Whh) -> fp32-equivalent
// per-step precision (R3/R5/R6/R7: passed, absmax 9.8e-4).
//
// R8 structure (R5-R7 were bound by ~64 dependent L3 round trips/step: full
// 256KB h read per WG through invalidated caches with shallow pipelining):
//  - 256 WGs = 4 row-groups x 64 col-groups; each computes a 16x16 h-tile.
//    Row split exploits h_t[n,:] depending only on h_{t-1}[n,:]:
//    per-WG A = 16 rows x 1024 x hi/lo = 64 KB -> fits in LDS.
//  - A staged per step via 16x global_load_lds (16B): zero VGPR cost, fully
//    pipelined issue, single vmcnt drain -> ~1 L3 round trip instead of ~64.
//  - K split 4-ways across the 4 waves; partials LDS-reduced; epilogue
//    distributed 1 output/thread (2 bypass stores/lane).
//  - tokens prefetched 1 step ahead (x immutable -> fence-safe).
//  - poll only own row-group's 64 producers; flags persist across chunks.

typedef _Float16 f16x8 __attribute__((ext_vector_type(8)));
typedef float    f32x4 __attribute__((ext_vector_type(4)));

#define NSEQ  64
#define TSEQ  1024
#define HDIM  1024
#define VOCABSZ 256
#define ODIM  256
#define RG    4        // row groups (16 rows each)
#define CG    64       // col groups (16 cols each)
#define NWGS  (RG*CG)  // 256
#define LOSCALE 2048.0f
#define LOINV  (1.0f/2048.0f)

// hbuf layout: [buf(2)][plane(2: hi,lo)][NSEQ][HDIM] fp16
#define HPLANE (NSEQ * HDIM)
#define HBUFSZ (2 * HPLANE)

#define AS1 __attribute__((address_space(1)))
#define AS3 __attribute__((address_space(3)))

// ---------------------------------------------------------------- init / prep
__global__ __launch_bounds__(256) void rnn_init(
    const float* __restrict__ Whh, const float* __restrict__ Wout,
    _Float16* __restrict__ whhT_hi, _Float16* __restrict__ whhT_lo,
    _Float16* __restrict__ woutT,
    _Float16* __restrict__ hbuf, unsigned* __restrict__ flags)
{
    int i = blockIdx.x * 256 + threadIdx.x;
    int stride = gridDim.x * 256;
    for (int idx = i; idx < HDIM * HDIM; idx += stride) {
        int j = idx >> 10, k = idx & 1023;
        float w = Whh[k * HDIM + j];
        _Float16 hi = (_Float16)w;
        whhT_hi[idx] = hi;
        whhT_lo[idx] = (_Float16)((w - (float)hi) * LOSCALE);
    }
    for (int idx = i; idx < ODIM * HDIM; idx += stride) {
        int o = idx >> 10, k = idx & 1023;
        woutT[idx] = (_Float16)Wout[k * ODIM + o];
    }
    for (int idx = i; idx < 2 * HBUFSZ; idx += stride) hbuf[idx] = (_Float16)0.f;
    for (int idx = i; idx < TSEQ * NWGS; idx += stride) flags[idx] = 0u;
}

// ---------------------------------------------------------------- recurrence
__global__ __launch_bounds__(256, 1) void rnn_steps(
    const int*   __restrict__ x,          // [NSEQ][TSEQ]
    const float* __restrict__ E,          // [VOCAB][HDIM]
    const float* __restrict__ bh,         // [HDIM]
    const _Float16* __restrict__ whhT_hi, // [HDIM][HDIM] j-major
    const _Float16* __restrict__ whhT_lo,
    _Float16* __restrict__ hbuf,
    unsigned* __restrict__ flags,         // [TSEQ][RG][CG]
    _Float16* __restrict__ z,             // chunk: [tc][NSEQ*HDIM]
    float* __restrict__ hlast_out,        // [NSEQ*HDIM]
    int t0, int t1)
{
    const int bid  = blockIdx.x;
    const int rg   = bid & 3;          // row group 0..3
    const int cg   = bid >> 2;         // col group 0..63
    const int j0   = cg * 16;
    const int rbase= rg * 16;
    const int tid  = threadIdx.x;
    const int lane = tid & 63;
    const int w    = tid >> 6;         // wave 0..3 = k-quarter = epilogue row sub
    const int lr   = lane & 15;
    const int lq   = lane >> 4;

    __shared__ _Float16 ldsA[2][16][HDIM];   // 64 KB  A (h rows) hi/lo
    __shared__ _Float16 bls[2][32][64][8];   // 64 KB  Whh^T fragments hi/lo
    __shared__ float    e_s[VOCABSZ][16];    // 16 KB  (E + bh) slice
    __shared__ f32x4    red[4][64];          //  4 KB  k-quarter partials

    {   // stage E[:, j0:j0+16] + bh fold (one-time)
        const float* src = E + (size_t)tid * HDIM + j0;
        #pragma unroll
        for (int jj = 0; jj < 16; ++jj) e_s[tid][jj] = src[jj] + bh[j0 + jj];
    }
    {   // stage B fragments (one-time): wave w stages m = w*8 .. w*8+7
        const size_t boff = (size_t)(j0 + lr) * HDIM + lq * 8;
        #pragma unroll
        for (int mm = 0; mm < 8; ++mm) {
            const int m = w * 8 + mm;
            *(f16x8*)&bls[0][m][lane][0] = *(const f16x8*)(whhT_hi + boff + m * 32);
            *(f16x8*)&bls[1][m][lane][0] = *(const f16x8*)(whhT_lo + boff + m * 32);
        }
    }
    __syncthreads();

    const int myrow = lq * 4 + w;          // local row this thread finalizes
    const int gn    = rbase + myrow;       // global sequence row
    const int jcol  = j0 + lr;             // global column this thread owns
    int tok_next = x[(size_t)gn * TSEQ + t0];

    for (int t = t0; t < t1; ++t) {
        const int tokv = tok_next;
        {   // prefetch next step's token (x immutable -> safe across fence)
            int tn = (t + 1 < TSEQ) ? t + 1 : TSEQ - 1;
            tok_next = x[(size_t)gn * TSEQ + tn];
        }

        if (t > 0) {
            // wait for the 64 producers of this row group (step t-1)
            unsigned* f = flags + (size_t)(t - 1) * NWGS + rg * CG;
            while (!__all((int)(__hip_atomic_load(&f[lane], __ATOMIC_RELAXED,
                                                  __HIP_MEMORY_SCOPE_AGENT) != 0u)))
                __builtin_amdgcn_s_sleep(1);
            // one invalidate so staged loads can't hit stale L1/L2
            __builtin_amdgcn_fence(__ATOMIC_ACQUIRE, "agent");
        }
        const _Float16* hin_hi  = hbuf + (size_t)( t      & 1) * HBUFSZ;
        const _Float16* hin_lo  = hin_hi + HPLANE;
        _Float16*       hout_hi = hbuf + (size_t)((t + 1) & 1) * HBUFSZ;
        _Float16*       hout_lo = hout_hi + HPLANE;

        // ---- stage A (16 rows x 1024, hi+lo) into LDS: 16 global_load_lds
        {
            const char* srcH = (const char*)(hin_hi + (size_t)rbase * HDIM);
            const char* srcL = (const char*)(hin_lo + (size_t)rbase * HDIM);
            char* dA0 = (char*)&ldsA[0][0][0];
            char* dA1 = (char*)&ldsA[1][0][0];
            const int tb = tid * 16;        // per-lane source byte offset
            const int wb = w * 1024;        // wave-uniform LDS base part
            #pragma unroll
            for (int i = 0; i < 8; ++i)
                __builtin_amdgcn_global_load_lds(
                    (const AS1 void*)(srcH + i * 4096 + tb),
                    (AS3 void*)(dA0 + i * 4096 + wb), 16, 0, 0);
            #pragma unroll
            for (int i = 0; i < 8; ++i)
                __builtin_amdgcn_global_load_lds(
                    (const AS1 void*)(srcL + i * 4096 + tb),
                    (AS3 void*)(dA1 + i * 4096 + wb), 16, 0, 0);
        }
        __syncthreads();   // compiler drains vmcnt before the barrier

        // ---- MFMA: wave w does k in [w*256, +256) of the 16x16 tile
        f32x4 acc0 = {0.f, 0.f, 0.f, 0.f};
        f32x4 acc1 = {0.f, 0.f, 0.f, 0.f};
        #pragma unroll
        for (int i = 0; i < 8; ++i) {
            const int m = w * 8 + i;
            const int ko = w * 256 + i * 32 + lq * 8;
            f16x8 ah  = *(const f16x8*)&ldsA[0][lr][ko];
            f16x8 al  = *(const f16x8*)&ldsA[1][lr][ko];
            f16x8 bh2 = *(const f16x8*)&bls[0][m][lane][0];
            f16x8 bl2 = *(const f16x8*)&bls[1][m][lane][0];
            acc0 = __builtin_amdgcn_mfma_f32_16x16x32_f16(ah, bh2, acc0, 0, 0, 0);
            acc1 = __builtin_amdgcn_mfma_f32_16x16x32_f16(al, bh2, acc1, 0, 0, 0);
            acc1 = __builtin_amdgcn_mfma_f32_16x16x32_f16(ah, bl2, acc1, 0, 0, 0);
        }
        f32x4 part;
        #pragma unroll
        for (int r = 0; r < 4; ++r) part[r] = acc0[r] + acc1[r] * LOINV;
        red[w][lane] = part;
        __syncthreads();

        // ---- epilogue: one output value per thread: (row=lq*4+w, col=lr)
        float s = 0.f;
        #pragma unroll
        for (int kq = 0; kq < 4; ++kq)
            s += ((const float*)&red[kq][lane])[w];
        float pre = s + e_s[tokv][lr];
        float hv  = tanhf(pre);
        _Float16 h16 = (_Float16)hv;
        _Float16 l16 = (_Float16)((hv - (float)h16) * LOSCALE);

        // cached stores (z, hlast)
        z[(size_t)(t - t0) * HPLANE + (size_t)gn * HDIM + jcol] = h16;
        if (t == TSEQ - 1) hlast_out[(size_t)gn * HDIM + jcol] = hv;

        // h exchange: bypass L1/L2 (sc0 sc1) -> at agent coherence point once
        // vmcnt(0) clears; no release fence needed.
        {
            union { _Float16 f; unsigned short u; } uh{h16}, ul{l16};
            const _Float16* ph = hout_hi + (size_t)gn * HDIM + jcol;
            const _Float16* pl = hout_lo + (size_t)gn * HDIM + jcol;
            unsigned vh = uh.u, vl = ul.u;
            asm volatile(
                "global_store_short %[ph], %[vh], off sc0 sc1\n\t"
                "global_store_short %[pl], %[vl], off sc0 sc1\n\t"
                "s_waitcnt vmcnt(0)"
                :
                : [ph]"v"(ph), [pl]"v"(pl), [vh]"v"(vh), [vl]"v"(vl)
                : "memory");
        }
        __syncthreads();     // all 256 outputs drained
        if (tid == 0)
            __hip_atomic_store(&flags[(size_t)t * NWGS + rg * CG + cg], 1u,
                               __ATOMIC_RELAXED, __HIP_MEMORY_SCOPE_AGENT);
    }
}

// ---------------------------------------------------------------- output GEMM + softmax
__global__ __launch_bounds__(256, 1) void rnn_out(
    const _Float16* __restrict__ z,      // chunk: [tc][NSEQ*HDIM]
    const _Float16* __restrict__ woutT,  // [ODIM][HDIM]
    const float* __restrict__ bout,      // [ODIM]
    float* __restrict__ y,               // [NSEQ][TSEQ][ODIM]
    int t0, int tc)
{
    const int b = blockIdx.x;
    const int t_rel = b >> 2, ng = b & 3;
    const int t = t0 + t_rel;
    const int n0 = ng * 16;
    const int tid = threadIdx.x;
    const int lane = tid & 63, wv = tid >> 6;
    const int lr = lane & 15, lq = lane >> 4;

    __shared__ float lg[16][ODIM + 8];   // logits staging

    const _Float16* abase = z + (size_t)t_rel * (NSEQ * HDIM)
                              + (size_t)(n0 + lr) * HDIM + lq * 8;
    f16x8 af[32];
    #pragma unroll
    for (int m = 0; m < 32; ++m) af[m] = *(const f16x8*)(abase + m * 32);

    #pragma unroll
    for (int i = 0; i < 4; ++i) {
        int ot = (wv * 4 + i) * 16;
        const _Float16* bbase = woutT + (size_t)(ot + lr) * HDIM + lq * 8;
        f32x4 acc = {0.f, 0.f, 0.f, 0.f};
        #pragma unroll
        for (int m = 0; m < 32; ++m) {
            f16x8 bfr = *(const f16x8*)(bbase + m * 32);
            acc = __builtin_amdgcn_mfma_f32_16x16x32_f16(af[m], bfr, acc, 0, 0, 0);
        }
        #pragma unroll
        for (int r = 0; r < 4; ++r)
            lg[lq * 4 + r][ot + lr] = acc[r];
    }
    __syncthreads();

    for (int rr = 0; rr < 4; ++rr) {
        int row = wv * 4 + rr;
        int n = n0 + row;
        float v0 = lg[row][lane]       + bout[lane];
        float v1 = lg[row][64 + lane]  + bout[64 + lane];
        float v2 = lg[row][128 + lane] + bout[128 + lane];
        float v3 = lg[row][192 + lane] + bout[192 + lane];
        float mx = fmaxf(fmaxf(v0, v1), fmaxf(v2, v3));
        for (int s = 32; s > 0; s >>= 1) mx = fmaxf(mx, __shfl_xor(mx, s));
        float e0 = __expf(v0 - mx), e1 = __expf(v1 - mx);
        float e2 = __expf(v2 - mx), e3 = __expf(v3 - mx);
        float sm = e0 + e1 + e2 + e3;
        for (int s = 32; s > 0; s >>= 1) sm += __shfl_xor(sm, s);
        float inv = 1.f / sm;
        float* dst = y + ((size_t)n * TSEQ + t) * ODIM;
        dst[lane]       = e0 * inv;
        dst[64 + lane]  = e1 * inv;
        dst[128 + lane] = e2 * inv;
        dst[192 + lane] = e3 * inv;
    }
}

// ---------------------------------------------------------------- launch
extern "C" void kernel_launch(void* const* d_in, const int* in_sizes, int n_in,
                              void* d_out, int out_size, void* d_ws, size_t ws_size,
                              hipStream_t stream)
{
    const int*   x    = (const int*)  d_in[0];
    const float* E    = (const float*)d_in[1];
    const float* Whh  = (const float*)d_in[2];
    const float* bh   = (const float*)d_in[3];
    const float* Wout = (const float*)d_in[4];
    const float* bout = (const float*)d_in[5];

    float* y     = (float*)d_out;
    float* hlast = y + (size_t)NSEQ * TSEQ * ODIM;

    char* ws = (char*)d_ws;
    size_t off = 0;
    auto alloc = [&](size_t bytes) -> void* {
        void* p = ws + off;
        off = (off + bytes + 255) & ~(size_t)255;
        return p;
    };
    _Float16* whhT_hi = (_Float16*)alloc((size_t)HDIM * HDIM * 2);
    _Float16* whhT_lo = (_Float16*)alloc((size_t)HDIM * HDIM * 2);
    _Float16* woutT   = (_Float16*)alloc((size_t)ODIM * HDIM * 2);
    _Float16* hbuf    = (_Float16*)alloc((size_t)2 * HBUFSZ * 2);
    unsigned* flags   = (unsigned*)alloc((size_t)TSEQ * NWGS * 4);
    _Float16* z       = (_Float16*)(ws + off);

    size_t zcap = (ws_size > off) ? (ws_size - off) : 0;
    int tc_max = (int)(zcap / ((size_t)NSEQ * HDIM * 2));
    if (tc_max > TSEQ) tc_max = TSEQ;
    if (tc_max < 1)    tc_max = 1;

    rnn_init<<<2048, 256, 0, stream>>>(Whh, Wout, whhT_hi, whhT_lo, woutT,
                                       hbuf, flags);

    for (int t0 = 0; t0 < TSEQ; t0 += tc_max) {
        int tc = TSEQ - t0 < tc_max ? TSEQ - t0 : tc_max;
        rnn_steps<<<NWGS, 256, 0, stream>>>(x, E, bh, whhT_hi, whhT_lo, hbuf,
                                            flags, z, hlast, t0, t0 + tc);
        rnn_out<<<tc * 4, 256, 0, stream>>>(z, woutT, bout, y, t0, tc);
    }
}